// Round 13
// baseline (333.544 us; speedup 1.0000x reference)
//
#include <hip/hip_runtime.h>

// Embedding lookup sparse (combiner='sum') for MI355X.
// keys:  int32 [N=106496, NNZ=10]
// mask:  bool in reference -> delivered as int32 [N, NNZ] by the harness
// table: fp32  [VOCAB=1e6, DIM=64]  (~244 MiB)
// out:   fp32  [N, DIM]  == reshape(BATCH, SLOTS*DIM), same memory layout
//
// v4b = v3 (branchless ILP + row-0 redirect for masked gathers) + explicit
// non-temporal output stores (skip RFO on the 27 MB output, keep L2/L3
// capacity for table-row dedup) + nt loads for read-once keys/mask.
// NOTE: __builtin_nontemporal_* requires clang ext_vector types, not the
// HIP_vector_type structs (int2/float4) — hence the *_v aliases below.

constexpr int NNZ   = 10;
constexpr int NROWS = 4096 * 26;   // 106496
constexpr int DIM   = 64;

typedef int   int2_v   __attribute__((ext_vector_type(2)));
typedef float float4_v __attribute__((ext_vector_type(4)));

__global__ __launch_bounds__(256) void emb_pool_kernel(
    const int* __restrict__ keys,
    const int* __restrict__ mask,     // int32: 0 or 1 per (row, j)
    const float* __restrict__ table,
    float* __restrict__ out)
{
    const int tid      = threadIdx.x;
    const int g        = tid & 15;        // float4 slice within the row (16 B/lane)
    const int rowLocal = tid >> 4;        // 0..15
    const int row      = blockIdx.x * 16 + rowLocal;

    const int* krow = keys + (size_t)row * NNZ;
    const int* mrow = mask + (size_t)row * NNZ;

    // Key/mask rows are 40 B (8 B-aligned) -> int2 vector loads, read-once
    // streams -> non-temporal (don't displace table rows in L2/L3).
    int k[NNZ], m[NNZ];
#pragma unroll
    for (int j = 0; j < NNZ; j += 2) {
        int2_v kv = __builtin_nontemporal_load(
            reinterpret_cast<const int2_v*>(krow + j));
        int2_v mv = __builtin_nontemporal_load(
            reinterpret_cast<const int2_v*>(mrow + j));
        k[j] = kv.x; k[j + 1] = kv.y;
        m[j] = mv.x; m[j + 1] = mv.y;
    }

    // Redirect masked gathers to row 0 (one v_cndmask each, no divergence).
    // Row 0 is hit by ~30% of all gathers -> L1/L2 resident -> ~no HBM cost.
#pragma unroll
    for (int j = 0; j < NNZ; ++j) {
        k[j] = (m[j] != 0) ? k[j] : 0;
    }

    // All 10 gathers in flight at once (cached: duplicates + row 0 reuse).
    float4 v[NNZ];
#pragma unroll
    for (int j = 0; j < NNZ; ++j) {
        v[j] = *reinterpret_cast<const float4*>(
            table + (size_t)k[j] * DIM + g * 4);
    }

    float4 acc = make_float4(0.f, 0.f, 0.f, 0.f);
#pragma unroll
    for (int j = 0; j < NNZ; ++j) {
        const float mf = (float)m[j];   // 0.0f or 1.0f
        acc.x = fmaf(mf, v[j].x, acc.x);
        acc.y = fmaf(mf, v[j].y, acc.y);
        acc.z = fmaf(mf, v[j].z, acc.z);
        acc.w = fmaf(mf, v[j].w, acc.w);
    }

    // Full-line coalesced store (256 B per 16-lane group); non-temporal to
    // skip RFO and avoid polluting caches with write-once output.
    float4_v accv = { acc.x, acc.y, acc.z, acc.w };
    __builtin_nontemporal_store(
        accv, reinterpret_cast<float4_v*>(out + (size_t)row * DIM + g * 4));
}

extern "C" void kernel_launch(void* const* d_in, const int* in_sizes, int n_in,
                              void* d_out, int out_size, void* d_ws, size_t ws_size,
                              hipStream_t stream) {
    const int*   keys  = (const int*)d_in[0];
    const int*   mask  = (const int*)d_in[1];
    const float* table = (const float*)d_in[2];
    float*       out   = (float*)d_out;

    // 16 rows per 256-thread block; N = 106496 = 6656 * 16 (no tail).
    const int blocks = NROWS / 16;
    emb_pool_kernel<<<blocks, 256, 0, stream>>>(keys, mask, table, out);
}